// Round 6
// baseline (141.428 us; speedup 1.0000x reference)
//
#include <hip/hip_runtime.h>

#define H 1024
#define LEN 8192
#define V 50000
#define CHUNK 8
#define NCH (LEN / CHUNK)   // 1024 chunks per batch
#define NBH 512             // out-half streaming blocks
#define NTH 6250            // tiles of 8 rows over V

__device__ __forceinline__ float dot4(float4 a, float4 b) {
    return a.x * b.x + a.y * b.y + a.z * b.z + a.w * b.w;
}

__device__ __forceinline__ void gld_lds16(const float* g, float* l) {
    __builtin_amdgcn_global_load_lds(
        (const __attribute__((address_space(1))) void*)g,
        (__attribute__((address_space(3))) void*)l, 16, 0, 0);
}

// ---------------------------------------------------------------------------
// K1: fused pre-work.
//   blocks 0..63    : u[h] = sum_k v[k]*attn_w[k*2048+1024+h]
//   blocks 64..71   : embedding gather
//   blocks 72..1095 : GRU cell, one block per output element hh
// ---------------------------------------------------------------------------
__global__ void k_pre(const float* __restrict__ attn_w,
                      const float* __restrict__ v,
                      float* __restrict__ u,
                      const int* __restrict__ ids,
                      const float* __restrict__ emb,
                      float* __restrict__ out_emb,
                      const float* __restrict__ lctx,
                      const float* __restrict__ lhid,
                      const float* __restrict__ w_ih,
                      const float* __restrict__ w_hh,
                      const float* __restrict__ b_ih,
                      const float* __restrict__ b_hh,
                      float* __restrict__ o_hidden,
                      float* __restrict__ o_rnn) {
    __shared__ float red[16][16];
    __shared__ float lds[3][4][4];
    int bid = blockIdx.x;
    int t   = threadIdx.x;

    if (bid < 64) {
        int kg = t >> 4;            // 0..15
        int hi = t & 15;            // 0..15
        int h  = bid * 16 + hi;
        float acc = 0.f;
#pragma unroll 8
        for (int i = 0; i < 64; ++i) {
            int k = kg * 64 + i;
            acc += v[k] * attn_w[(long)k * (2 * H) + H + h];
        }
        red[kg][hi] = acc;
        __syncthreads();
        if (t < 16) {
            float s = 0.f;
#pragma unroll
            for (int g = 0; g < 16; ++g) s += red[g][t];
            u[bid * 16 + t] = s;
        }
        return;
    }
    if (bid < 72) {
        int idx = (bid - 64) * 256 + t;    // 0..2047
        int b = idx >> 10, h = idx & 1023;
        out_emb[idx] = emb[(long)ids[b] * H + h];
        return;
    }

    // ---- GRU ----
    int hh = bid - 72;            // 0..1023
    int kb = t * 8;               // x index base (0..2040)

    float4 x0a, x0b, x1a, x1b;
    if (kb < H) {
        const float* p0 = emb + (long)ids[0] * H + kb;
        const float* p1 = emb + (long)ids[1] * H + kb;
        x0a = *(const float4*)p0;       x0b = *(const float4*)(p0 + 4);
        x1a = *(const float4*)p1;       x1b = *(const float4*)(p1 + 4);
    } else {
        const float* p0 = lctx + (kb - H);
        const float* p1 = lctx + H + (kb - H);
        x0a = *(const float4*)p0;       x0b = *(const float4*)(p0 + 4);
        x1a = *(const float4*)p1;       x1b = *(const float4*)(p1 + 4);
    }
    int kb2 = t * 4;              // h index base (0..1020)
    float4 h0 = *(const float4*)(lhid + kb2);
    float4 h1 = *(const float4*)(lhid + H + kb2);

    for (int g = 0; g < 3; ++g) {
        const float* wi = w_ih + ((long)g * H + hh) * (2 * H) + kb;
        const float* wh = w_hh + ((long)g * H + hh) * H + kb2;
        float4 wa = *(const float4*)wi;
        float4 wb = *(const float4*)(wi + 4);
        float4 wc = *(const float4*)wh;
        float a0 = dot4(wa, x0a) + dot4(wb, x0b);
        float a1 = dot4(wa, x1a) + dot4(wb, x1b);
        float c0 = dot4(wc, h0);
        float c1 = dot4(wc, h1);
        for (int off = 32; off; off >>= 1) {
            a0 += __shfl_down(a0, off, 64);
            a1 += __shfl_down(a1, off, 64);
            c0 += __shfl_down(c0, off, 64);
            c1 += __shfl_down(c1, off, 64);
        }
        if ((t & 63) == 0) {
            int w = t >> 6;
            lds[g][w][0] = a0; lds[g][w][1] = a1;
            lds[g][w][2] = c0; lds[g][w][3] = c1;
        }
    }
    __syncthreads();
    if (t == 0) {
        float gx[3][2], gh[3][2];
        for (int g = 0; g < 3; ++g) {
            float s0 = 0, s1 = 0, s2 = 0, s3 = 0;
            for (int w = 0; w < 4; ++w) {
                s0 += lds[g][w][0]; s1 += lds[g][w][1];
                s2 += lds[g][w][2]; s3 += lds[g][w][3];
            }
            float bi = b_ih[g * H + hh], bh = b_hh[g * H + hh];
            gx[g][0] = s0 + bi; gx[g][1] = s1 + bi;
            gh[g][0] = s2 + bh; gh[g][1] = s3 + bh;
        }
        for (int b = 0; b < 2; ++b) {
            float r  = 1.f / (1.f + expf(-(gx[0][b] + gh[0][b])));
            float z  = 1.f / (1.f + expf(-(gx[1][b] + gh[1][b])));
            float n  = tanhf(gx[2][b] + r * gh[2][b]);
            float hp = lhid[b * H + hh];
            float hn = (1.f - z) * n + z * hp;
            o_hidden[b * H + hh] = hn;
            o_rnn[b * H + hh]    = hn;
        }
    }
}

// ---------------------------------------------------------------------------
// K2: mega-kernel — overlaps two independent HBM streams in one grid:
//   bid%5==0 (512 blocks): out partial, hnew-half: part[b,o]=hnew_b . W_h[o]
//                          (staged dbuf tiles of 8 half-rows of out_w)
//   else    (2048 blocks): flash-style ctx chunk (8 enc rows staged in LDS,
//                          energies from LDS, local softmax, partial vec)
// LDS: 72 KB shared carve -> 2 blocks/CU either way.
// ---------------------------------------------------------------------------
__global__ void __launch_bounds__(256)
k_mid(const float* __restrict__ enc,
      const float* __restrict__ u,
      float* __restrict__ pvec,
      float* __restrict__ marr,
      float* __restrict__ sarr,
      const float* __restrict__ ow,
      const float* __restrict__ hnew,
      float* __restrict__ part) {
    __shared__ float smem[18432];    // 72 KB
    int t    = threadIdx.x;
    int lane = t & 63;
    int wv   = t >> 6;
    int bid  = blockIdx.x;
    int r5   = bid % 5;
    int q5   = bid / 5;

    if (r5 == 0) {
        // ---- out_h partial: q5 in 0..511 ----
        float* cat0 = smem;                   // 1024
        float* cat1 = smem + H;               // 1024
        float* wtA  = smem + 2 * H;           // 8192
        float* wtB  = smem + 10 * H;          // 8192
        ((float4*)cat0)[t] = ((const float4*)hnew)[t];
        ((float4*)cat1)[t] = ((const float4*)(hnew + H))[t];
        {
            const float* srcb = ow + (long)q5 * 8 * (2 * H);
#pragma unroll
            for (int i = 0; i < 8; ++i)
                gld_lds16(srcb + (long)i * (2 * H) + t * 4, wtA + i * H + t * 4);
        }
        __syncthreads();
        int buf = 0;
        for (int T = q5; T < NTH; T += NBH) {
            int Tn = T + NBH;
            if (Tn < NTH) {
                const float* srcb = ow + (long)Tn * 8 * (2 * H);
                float* dst = buf ? wtA : wtB;
#pragma unroll
                for (int i = 0; i < 8; ++i)
                    gld_lds16(srcb + (long)i * (2 * H) + t * 4, dst + i * H + t * 4);
            }
            const float* w = buf ? wtB : wtA;
#pragma unroll
            for (int rr = 0; rr < 2; ++rr) {
                int r = wv * 2 + rr;
                const float4* wr = (const float4*)(w + r * H);
                float a0 = 0.f, a1 = 0.f;
#pragma unroll
                for (int j = 0; j < 4; ++j) {
                    float4 ww = wr[lane + 64 * j];
                    a0 += dot4(ww, ((const float4*)cat0)[lane + 64 * j]);
                    a1 += dot4(ww, ((const float4*)cat1)[lane + 64 * j]);
                }
                for (int off = 32; off; off >>= 1) {
                    a0 += __shfl_down(a0, off, 64);
                    a1 += __shfl_down(a1, off, 64);
                }
                if (lane == 0) {
                    long row = (long)T * 8 + r;
                    part[row]     = a0;
                    part[V + row] = a1;
                }
            }
            __syncthreads();
            buf ^= 1;
        }
        return;
    }

    // ---- ctx chunk: cidx in 0..2047 ----
    int cidx = q5 * 4 + (r5 - 1);
    int b  = cidx >> 10;
    int ch = cidx & 1023;
    float* erow = smem;                  // 8192 floats
    float* elds = smem + CHUNK * H;      // 8 floats

    const float* src = enc + ((long)b * LEN + (long)ch * CHUNK) * H;
#pragma unroll
    for (int i = 0; i < CHUNK; ++i)
        gld_lds16(src + i * H + t * 4, erow + i * H + t * 4);

    float4 uf[4];
#pragma unroll
    for (int c = 0; c < 4; ++c)
        uf[c] = *(const float4*)(u + c * 256 + lane * 4);

    __syncthreads();

#pragma unroll
    for (int rr = 0; rr < 2; ++rr) {
        int r = wv * 2 + rr;
        float acc = 0.f;
#pragma unroll
        for (int c = 0; c < 4; ++c) {
            float4 ev = *(const float4*)(erow + r * H + c * 256 + lane * 4);
            acc += dot4(ev, uf[c]);
        }
        for (int off = 32; off; off >>= 1) acc += __shfl_down(acc, off, 64);
        if (lane == 0) elds[r] = acc;
    }
    __syncthreads();

    float m = elds[0];
#pragma unroll
    for (int r = 1; r < CHUNK; ++r) m = fmaxf(m, elds[r]);
    float p[CHUNK];
    float s = 0.f;
#pragma unroll
    for (int r = 0; r < CHUNK; ++r) { p[r] = expf(elds[r] - m); s += p[r]; }

    float4 acc = {0.f, 0.f, 0.f, 0.f};
#pragma unroll
    for (int r = 0; r < CHUNK; ++r) {
        float4 ev = *(const float4*)(erow + r * H + t * 4);
        acc.x += p[r] * ev.x; acc.y += p[r] * ev.y;
        acc.z += p[r] * ev.z; acc.w += p[r] * ev.w;
    }
    *(float4*)(pvec + (long)cidx * H + t * 4) = acc;
    if (t == 0) { marr[cidx] = m; sarr[cidx] = s; }
}

// ---------------------------------------------------------------------------
// K3: flash combine. 64 blocks; block = (b, 32 h's).
// ---------------------------------------------------------------------------
__global__ void __launch_bounds__(256)
k_red(const float* __restrict__ pvec,
      const float* __restrict__ marr,
      const float* __restrict__ sarr,
      float* __restrict__ out_ctx) {
    __shared__ float scale[NCH];        // 4 KB
    __shared__ float red[8][32];
    int t  = threadIdx.x;
    int b  = blockIdx.x >> 5;           // 0..1
    int h0 = (blockIdx.x & 31) * 32;
    const float* mb = marr + b * NCH;
    const float* sb = sarr + b * NCH;

    float m = -3.4e38f;
    for (int i = t; i < NCH; i += 256) m = fmaxf(m, mb[i]);
    for (int off = 32; off; off >>= 1) m = fmaxf(m, __shfl_xor(m, off, 64));
    if ((t & 63) == 0) red[0][t >> 6] = m;
    __syncthreads();
    m = fmaxf(fmaxf(red[0][0], red[0][1]), fmaxf(red[0][2], red[0][3]));
    __syncthreads();

    float d = 0.f;
    for (int i = t; i < NCH; i += 256) {
        float sc = expf(mb[i] - m);
        scale[i] = sc;
        d += sc * sb[i];
    }
    for (int off = 32; off; off >>= 1) d += __shfl_xor(d, off, 64);
    if ((t & 63) == 0) red[0][t >> 6] = d;
    __syncthreads();
    float inv = 1.f / (red[0][0] + red[0][1] + red[0][2] + red[0][3]);
    __syncthreads();

    int grp = t >> 5, il = t & 31;
    const float* pv = pvec + (long)b * NCH * H + (h0 + il);
    float acc = 0.f;
#pragma unroll 4
    for (int c = grp * 128; c < grp * 128 + 128; ++c)
        acc += scale[c] * pv[(long)c * H];
    red[grp][il] = acc;
    __syncthreads();
    if (t < 32) {
        float ssum = 0.f;
#pragma unroll
        for (int g = 0; g < 8; ++g) ssum += red[g][t];
        out_ctx[b * H + h0 + t] = ssum * inv;
    }
}

// ---------------------------------------------------------------------------
// K4: ctx-half of output projection + bias + partial -> final.
// Same staged structure as k_mid's out_h path, column offset +H.
// grid 512 x 256
// ---------------------------------------------------------------------------
__global__ void __launch_bounds__(256)
k_outc(const float* __restrict__ ow,
       const float* __restrict__ ob,
       const float* __restrict__ ctx,
       const float* __restrict__ part,
       float* __restrict__ out) {
    __shared__ float smem[18432];    // 72 KB
    int t    = threadIdx.x;
    int lane = t & 63;
    int wv   = t >> 6;
    int q    = blockIdx.x;           // 0..511

    float* cat0 = smem;
    float* cat1 = smem + H;
    float* wtA  = smem + 2 * H;
    float* wtB  = smem + 10 * H;
    ((float4*)cat0)[t] = ((const float4*)ctx)[t];
    ((float4*)cat1)[t] = ((const float4*)(ctx + H))[t];
    {
        const float* srcb = ow + (long)q * 8 * (2 * H) + H;
#pragma unroll
        for (int i = 0; i < 8; ++i)
            gld_lds16(srcb + (long)i * (2 * H) + t * 4, wtA + i * H + t * 4);
    }
    __syncthreads();
    int buf = 0;
    for (int T = q; T < NTH; T += NBH) {
        int Tn = T + NBH;
        if (Tn < NTH) {
            const float* srcb = ow + (long)Tn * 8 * (2 * H) + H;
            float* dst = buf ? wtA : wtB;
#pragma unroll
            for (int i = 0; i < 8; ++i)
                gld_lds16(srcb + (long)i * (2 * H) + t * 4, dst + i * H + t * 4);
        }
        const float* w = buf ? wtB : wtA;
#pragma unroll
        for (int rr = 0; rr < 2; ++rr) {
            int r = wv * 2 + rr;
            const float4* wr = (const float4*)(w + r * H);
            float a0 = 0.f, a1 = 0.f;
#pragma unroll
            for (int j = 0; j < 4; ++j) {
                float4 ww = wr[lane + 64 * j];
                a0 += dot4(ww, ((const float4*)cat0)[lane + 64 * j]);
                a1 += dot4(ww, ((const float4*)cat1)[lane + 64 * j]);
            }
            for (int off = 32; off; off >>= 1) {
                a0 += __shfl_down(a0, off, 64);
                a1 += __shfl_down(a1, off, 64);
            }
            if (lane == 0) {
                long row = (long)T * 8 + r;
                float bb = ob[row];
                out[row]     = part[row]     + a0 + bb;
                out[V + row] = part[V + row] + a1 + bb;
            }
        }
        __syncthreads();
        buf ^= 1;
    }
}

extern "C" void kernel_launch(void* const* d_in, const int* in_sizes, int n_in,
                              void* d_out, int out_size, void* d_ws, size_t ws_size,
                              hipStream_t stream) {
    const int*   ids    = (const int*)  d_in[0];
    const float* lctx   = (const float*)d_in[1];
    const float* lhid   = (const float*)d_in[2];
    const float* enc    = (const float*)d_in[3];
    const float* emb    = (const float*)d_in[4];
    const float* w_ih   = (const float*)d_in[5];
    const float* w_hh   = (const float*)d_in[6];
    const float* b_ih   = (const float*)d_in[7];
    const float* b_hh   = (const float*)d_in[8];
    const float* attn_w = (const float*)d_in[9];
    // d_in[10] = attn_b  (unused: shift-invariant under softmax)
    const float* v      = (const float*)d_in[11];
    const float* out_w  = (const float*)d_in[12];
    const float* out_b  = (const float*)d_in[13];

    float* out_f       = (float*)d_out;
    float* o_output    = out_f;             // (2,1,50000) = 100000
    float* o_context   = out_f + 100000;    // (2,1,1024)  = 2048
    float* o_hidden    = out_f + 102048;    // (1,2,1024)  = 2048
    float* o_embedded  = out_f + 104096;    // (2,1,1024)  = 2048
    float* o_rnn       = out_f + 106144;    // (2,1,1024)  = 2048

    float* ws   = (float*)d_ws;
    float* U    = ws;                    // 1024
    float* MARR = ws + 1024;             // 2048
    float* SARR = ws + 3072;             // 2048
    float* PVEC = ws + 5120;             // 2048*1024
    float* PART = ws + 5120 + 2048 * 1024;  // 100000  (~9 MB total)

    k_pre <<<1096, 256, 0, stream>>>(attn_w, v, U, ids, emb, o_embedded,
                                     lctx, lhid, w_ih, w_hh, b_ih, b_hh,
                                     o_hidden, o_rnn);
    k_mid <<<2560, 256, 0, stream>>>(enc, U, PVEC, MARR, SARR,
                                     out_w, o_hidden, PART);
    k_red <<<64,   256, 0, stream>>>(PVEC, MARR, SARR, o_context);
    k_outc<<<512,  256, 0, stream>>>(out_w, out_b, o_context, PART, o_output);
}